// Round 1
// baseline (225.384 us; speedup 1.0000x reference)
//
#include <hip/hip_runtime.h>

// NodeBlock: agg = segment_sum(edges[1.6M,64], recv -> 50000 nodes)
//            X = [agg | nodes] (globals folded into bias)  (50000 x 192) bf16
//            out = relu(X@W1[:192]+b1') @ W2 + b2          (f32, 50000 x 128)
//
// R20: fuse build_x + mlp into one kernel (X tile lives in LDS, never hits
// global). Globals contribution folded into b1' = b1 + g@W1[192:256] (f32
// exact, computed in prep). Gather deepened to 8 in-flight 256B loads/wave
// to compensate for 2-blocks/CU occupancy (LDS 61.4 KB).
// Prev ledger: build_x 83 | mlp 40 | scatter+regroup 22 | small+gaps ~23.

typedef __bf16 bf16x8 __attribute__((ext_vector_type(8)));
typedef __bf16 bf16x4 __attribute__((ext_vector_type(4)));
typedef __bf16 bf16x2 __attribute__((ext_vector_type(2)));
typedef float f32x4 __attribute__((ext_vector_type(4)));
typedef int i32x4 __attribute__((ext_vector_type(4)));

#define EDGE_DIM 64
#define NODE_DIM 128
#define XDIM 192     // agg(64) | nodes(128); globals folded into bias
#define XPAD 200     // row stride bf16: 400B -> dword stride 100, %32=4 -> 2-way (free)
#define HID_DIM 256
#define OUT_DIM 128
#define NBUCKET 512
#define NPB 98       // nodes per bucket: 512*98 = 50176 >= 50000; local < 128 (7 bits)
#define EPB 4096     // edges per hist/scatter block (256 thr x 16)
#define MT 64        // M-tile of fused kernel
#define HPAD 280     // Hs row stride (bf16)

// ---------------- K1: weight prep (+bias fold) + per-block bucket histogram --
__global__ __launch_bounds__(256) void prep_hist_kernel(
    const float* __restrict__ W1, const float* __restrict__ b1,
    const float* __restrict__ W2, const float* __restrict__ glob,
    __bf16* __restrict__ W1T, float* __restrict__ b1f, __bf16* __restrict__ W2T,
    const int* __restrict__ recv, int* __restrict__ bh, int n_edges) {
  const int b = blockIdx.x, t = threadIdx.x;
  if (b < HID_DIM) {
    if (t < XDIM) {
      W1T[b * XDIM + t] = (__bf16)W1[t * HID_DIM + b];
    } else {
      // threads 192..255 == wave 3: fold globals into bias (f32 exact)
      float p = glob[t - XDIM] * W1[t * HID_DIM + b];
      for (int off = 32; off; off >>= 1) p += __shfl_xor(p, off, 64);
      if (t == XDIM) b1f[b] = b1[b] + p;
    }
    return;
  }
  if (b < HID_DIM + OUT_DIM) {
    int nn = b - HID_DIM;
    W2T[nn * HID_DIM + t] = (__bf16)W2[t * OUT_DIM + nn];
    return;
  }
  const int hb = b - (HID_DIM + OUT_DIM);
  __shared__ int h[NBUCKET];
  for (int k = t; k < NBUCKET; k += 256) h[k] = 0;
  __syncthreads();
  const int i0 = hb * EPB + t * 16;
  if (i0 + 16 <= n_edges) {
#pragma unroll
    for (int c = 0; c < 4; ++c) {
      i32x4 r4 = *(const i32x4*)(recv + i0 + c * 4);
      atomicAdd(&h[r4.x / NPB], 1);
      atomicAdd(&h[r4.y / NPB], 1);
      atomicAdd(&h[r4.z / NPB], 1);
      atomicAdd(&h[r4.w / NPB], 1);
    }
  } else {
    for (int j = 0; j < 16; ++j)
      if (i0 + j < n_edges) atomicAdd(&h[recv[i0 + j] / NPB], 1);
  }
  __syncthreads();
  for (int k = t; k < NBUCKET; k += 256) bh[(size_t)hb * NBUCKET + k] = h[k];
}

// ---------------- K2a: WAVE-PARALLEL column scan (one wave per bucket) ------
__global__ __launch_bounds__(256) void col_scan_kernel(
    int* __restrict__ bh, int* __restrict__ tot, int nbh) {
  const int bucket = (blockIdx.x * 256 + threadIdx.x) >> 6;
  const int lane = threadIdx.x & 63;
  int running = 0;
  for (int c = 0; c < nbh; c += 64) {
    const int k = c + lane;
    int v = (k < nbh) ? bh[(size_t)k * NBUCKET + bucket] : 0;
    int incl = v;
    for (int off = 1; off < 64; off <<= 1) {
      int y = __shfl_up(incl, off, 64);
      if (lane >= off) incl += y;
    }
    if (k < nbh) bh[(size_t)k * NBUCKET + bucket] = running + incl - v;
    running += __shfl(incl, 63, 64);
  }
  if (lane == 0) tot[bucket] = running;
}

// ---------------- K2b: base scan over 512 totals (1 block) ------------------
__global__ __launch_bounds__(512) void base_scan_kernel(const int* __restrict__ tot,
                                                        int* __restrict__ base) {
  const int b = threadIdx.x;
  int v = tot[b];
  __shared__ int sums[NBUCKET];
  sums[b] = v;
  __syncthreads();
  for (int off = 1; off < NBUCKET; off <<= 1) {
    int y = (b >= off) ? sums[b - off] : 0;
    __syncthreads();
    sums[b] += y;
    __syncthreads();
  }
  base[b] = sums[b] - v;  // exclusive
  if (b == NBUCKET - 1) base[NBUCKET] = sums[b];
}

// ---------------- K3: scatter packed (eid<<7)|local, LDS cursors ------------
__global__ __launch_bounds__(256) void scatter_kernel(
    const int* __restrict__ recv, const int* __restrict__ off,
    const int* __restrict__ base, int* __restrict__ sorted1, int n_edges) {
  const int kb = blockIdx.x, t = threadIdx.x;
  __shared__ int cur[NBUCKET];
  for (int k = t; k < NBUCKET; k += 256)
    cur[k] = base[k] + off[(size_t)kb * NBUCKET + k];
  __syncthreads();
  const int i0 = kb * EPB + t * 16;
  if (i0 + 16 <= n_edges) {
#pragma unroll
    for (int c = 0; c < 4; ++c) {
      i32x4 r4 = *(const i32x4*)(recv + i0 + c * 4);
      const int e0 = i0 + c * 4;
      int bk, p;
      bk = r4.x / NPB; p = atomicAdd(&cur[bk], 1);
      sorted1[p] = ((e0 + 0) << 7) | (r4.x - bk * NPB);
      bk = r4.y / NPB; p = atomicAdd(&cur[bk], 1);
      sorted1[p] = ((e0 + 1) << 7) | (r4.y - bk * NPB);
      bk = r4.z / NPB; p = atomicAdd(&cur[bk], 1);
      sorted1[p] = ((e0 + 2) << 7) | (r4.z - bk * NPB);
      bk = r4.w / NPB; p = atomicAdd(&cur[bk], 1);
      sorted1[p] = ((e0 + 3) << 7) | (r4.w - bk * NPB);
    }
  } else {
    for (int j = 0; j < 16; ++j) {
      const int i = i0 + j;
      if (i < n_edges) {
        int r = recv[i];
        int bk = r / NPB;
        int p = atomicAdd(&cur[bk], 1);
        sorted1[p] = (i << 7) | (r - bk * NPB);
      }
    }
  }
}

// ---------------- K4: regroup bucket pairs -> per-node eid lists ------------
__global__ __launch_bounds__(256) void regroup_kernel(
    const int* __restrict__ sorted1, const int* __restrict__ base,
    int* __restrict__ nodeoff, int* __restrict__ ncount,
    int* __restrict__ eidcsr, int n_nodes) {
  const int b = blockIdx.x, t = threadIdx.x;
  __shared__ int cnt[NPB];
  __shared__ int loff[NPB];
  if (t < NPB) cnt[t] = 0;
  __syncthreads();
  const int s = base[b], e = base[b + 1];
  const int nb_ = b * NPB;
  for (int j = s + t; j < e; j += 256) atomicAdd(&cnt[sorted1[j] & 127], 1);
  __syncthreads();
  if (t == 0) {
    int run = 0;
#pragma unroll
    for (int k = 0; k < NPB; ++k) { loff[k] = run; run += cnt[k]; }
  }
  __syncthreads();
  if (t < NPB) {
    const int node = nb_ + t;
    if (node < n_nodes) { nodeoff[node] = s + loff[t]; ncount[node] = cnt[t]; }
    cnt[t] = 0;  // reuse as cursor
  }
  __syncthreads();
  for (int j = s + t; j < e; j += 256) {
    const int p = sorted1[j];
    const int local = p & 127;
    const int slot = atomicAdd(&cnt[local], 1);
    eidcsr[s + loff[local] + slot] = p >> 7;
  }
}

// ---------------- K5: FUSED gather -> LDS X tile -> MLP ---------------------
#define NTLOAD(i) __builtin_nontemporal_load((const f32x4*)(edges + (size_t)(i) * EDGE_DIM + l15 * 4))

__global__ __launch_bounds__(256, 2) void fused_kernel(
    const float* __restrict__ edges, const int* __restrict__ nodeoff,
    const int* __restrict__ ncount, const int* __restrict__ eid,
    const float* __restrict__ nodes,
    const __bf16* __restrict__ W1T, const float* __restrict__ b1f,
    const __bf16* __restrict__ W2T, const float* __restrict__ b2,
    float* __restrict__ out, int M) {
  __shared__ __bf16 Xs[MT][XPAD];   // 25.6 KB
  __shared__ __bf16 Hs[MT][HPAD];   // 35.8 KB
  const int wave = threadIdx.x >> 6;
  const int lane = threadIdx.x & 63;
  const int q = lane >> 4;    // quarter-wave id (memory pipeline depth)
  const int l15 = lane & 15;
  const int lk = q;           // k-chunk id in MFMA fragments
  const int Mbase0 = blockIdx.x * MT;

  // ---- gather phase: wave w builds rows [w*16, w*16+16) of Xs -------------
  for (int r = wave * 16; r < wave * 16 + 16; ++r) {
    const int node = Mbase0 + r;
    int s = 0, e = 0;
    if (node < M) { s = nodeoff[node]; e = s + ncount[node]; }
    f32x4 z = {0.f, 0.f, 0.f, 0.f};
    f32x4 a0 = z, a1 = z, a2 = z, a3 = z, a4 = z, a5 = z, a6 = z, a7 = z;
    int j = s + q;
    int i0 = (j      < e) ? eid[j]      : 0;
    int i1 = (j + 4  < e) ? eid[j + 4]  : 0;
    int i2 = (j + 8  < e) ? eid[j + 8]  : 0;
    int i3 = (j + 12 < e) ? eid[j + 12] : 0;
    int i4 = (j + 16 < e) ? eid[j + 16] : 0;
    int i5 = (j + 20 < e) ? eid[j + 20] : 0;
    int i6 = (j + 24 < e) ? eid[j + 24] : 0;
    int i7 = (j + 28 < e) ? eid[j + 28] : 0;
    while (j + 28 < e) {  // 8 x 256B loads in flight per wave
      f32x4 v0 = NTLOAD(i0);
      f32x4 v1 = NTLOAD(i1);
      f32x4 v2 = NTLOAD(i2);
      f32x4 v3 = NTLOAD(i3);
      f32x4 v4 = NTLOAD(i4);
      f32x4 v5 = NTLOAD(i5);
      f32x4 v6 = NTLOAD(i6);
      f32x4 v7 = NTLOAD(i7);
      int n0 = (j + 32 < e) ? eid[j + 32] : 0;
      int n1 = (j + 36 < e) ? eid[j + 36] : 0;
      int n2 = (j + 40 < e) ? eid[j + 40] : 0;
      int n3 = (j + 44 < e) ? eid[j + 44] : 0;
      int n4 = (j + 48 < e) ? eid[j + 48] : 0;
      int n5 = (j + 52 < e) ? eid[j + 52] : 0;
      int n6 = (j + 56 < e) ? eid[j + 56] : 0;
      int n7 = (j + 60 < e) ? eid[j + 60] : 0;
      a0 += v0; a1 += v1; a2 += v2; a3 += v3;
      a4 += v4; a5 += v5; a6 += v6; a7 += v7;
      i0 = n0; i1 = n1; i2 = n2; i3 = n3;
      i4 = n4; i5 = n5; i6 = n6; i7 = n7;
      j += 32;
    }
    if (j      < e) a0 += NTLOAD(i0);
    if (j + 4  < e) a1 += NTLOAD(i1);
    if (j + 8  < e) a2 += NTLOAD(i2);
    if (j + 12 < e) a3 += NTLOAD(i3);
    if (j + 16 < e) a4 += NTLOAD(i4);
    if (j + 20 < e) a5 += NTLOAD(i5);
    if (j + 24 < e) a6 += NTLOAD(i6);

    a0 += a1; a2 += a3; a4 += a5; a6 += a7;
    a0 += a2; a4 += a6; a0 += a4;
#pragma unroll
    for (int c = 0; c < 4; ++c) {  // reduce across the 4 quarters
      float v = a0[c];
      v += __shfl_xor(v, 16, 64);
      v += __shfl_xor(v, 32, 64);
      a0[c] = v;
    }
    if (q == 0) {
      bf16x4 o;
      o[0] = (__bf16)a0[0]; o[1] = (__bf16)a0[1];
      o[2] = (__bf16)a0[2]; o[3] = (__bf16)a0[3];
      *(bf16x4*)(&Xs[r][l15 * 4]) = o;  // agg cols 0..63
    }
    bf16x2 nb;
    if (node < M) {
      float2 nv = *(const float2*)(nodes + (size_t)node * NODE_DIM + lane * 2);
      nb[0] = (__bf16)nv.x; nb[1] = (__bf16)nv.y;
    } else {
      nb[0] = (__bf16)0.f; nb[1] = (__bf16)0.f;
    }
    *(bf16x2*)(&Xs[r][EDGE_DIM + lane * 2]) = nb;  // node cols 64..191
  }
  __syncthreads();

  {  // phase 1: H = relu(Xs @ W1[:192] + b1') -> LDS (K = 192, 6 ks steps)
    bf16x8 B1[4][6];
    float bias1[4];
    const int colbase = wave * 64;
#pragma unroll
    for (int cb = 0; cb < 4; ++cb) {
      const int col = colbase + cb * 16 + l15;
      const __bf16* wrow = W1T + col * XDIM + lk * 8;
#pragma unroll
      for (int ks = 0; ks < 6; ++ks) B1[cb][ks] = *(const bf16x8*)(wrow + ks * 32);
      bias1[cb] = b1f[col];
    }
#pragma unroll
    for (int mb = 0; mb < 4; ++mb) {
      f32x4 acc[4];
#pragma unroll
      for (int cb = 0; cb < 4; ++cb) {
        f32x4 ini = {bias1[cb], bias1[cb], bias1[cb], bias1[cb]};
        acc[cb] = ini;
      }
      const __bf16* xrow = &Xs[mb * 16 + l15][lk * 8];
#pragma unroll
      for (int ks = 0; ks < 6; ++ks) {
        bf16x8 A = *(const bf16x8*)(xrow + ks * 32);
#pragma unroll
        for (int cb = 0; cb < 4; ++cb)
          acc[cb] = __builtin_amdgcn_mfma_f32_16x16x32_bf16(A, B1[cb][ks], acc[cb], 0, 0, 0);
      }
#pragma unroll
      for (int cb = 0; cb < 4; ++cb) {
#pragma unroll
        for (int r = 0; r < 4; ++r) {
          float v = acc[cb][r];
          Hs[mb * 16 + lk * 4 + r][colbase + cb * 16 + l15] = (__bf16)(v > 0.f ? v : 0.f);
        }
      }
    }
  }
  __syncthreads();
  {  // phase 2: out = H @ W2 + b2
    bf16x8 B2[2][8];
    float bias2[2];
    const int colbase = wave * 32;
#pragma unroll
    for (int cb = 0; cb < 2; ++cb) {
      const int col = colbase + cb * 16 + l15;
      const __bf16* wrow = W2T + col * HID_DIM + lk * 8;
#pragma unroll
      for (int ks = 0; ks < 8; ++ks) B2[cb][ks] = *(const bf16x8*)(wrow + ks * 32);
      bias2[cb] = b2[col];
    }
#pragma unroll
    for (int mb = 0; mb < 4; ++mb) {
      const int Mbase = Mbase0 + mb * 16;
      f32x4 acc[2];
#pragma unroll
      for (int cb = 0; cb < 2; ++cb) {
        f32x4 ini = {bias2[cb], bias2[cb], bias2[cb], bias2[cb]};
        acc[cb] = ini;
      }
#pragma unroll
      for (int ks = 0; ks < 8; ++ks) {
        bf16x8 A = *(const bf16x8*)(&Hs[mb * 16 + l15][lk * 8 + ks * 32]);
#pragma unroll
        for (int cb = 0; cb < 2; ++cb)
          acc[cb] = __builtin_amdgcn_mfma_f32_16x16x32_bf16(A, B2[cb][ks], acc[cb], 0, 0, 0);
      }
#pragma unroll
      for (int cb = 0; cb < 2; ++cb) {
        const int col = colbase + cb * 16 + l15;
#pragma unroll
        for (int r = 0; r < 4; ++r) {
          const int row = Mbase + lk * 4 + r;
          if (row < M) out[(size_t)row * OUT_DIM + col] = acc[cb][r];
        }
      }
    }
  }
}

extern "C" void kernel_launch(void* const* d_in, const int* in_sizes, int n_in,
                              void* d_out, int out_size, void* d_ws, size_t ws_size,
                              hipStream_t stream) {
  const float* edges    = (const float*)d_in[0];
  const int*   recv     = (const int*)d_in[1];
  const float* nodes    = (const float*)d_in[2];
  const float* globals_ = (const float*)d_in[3];
  const float* W1       = (const float*)d_in[5];
  const float* b1       = (const float*)d_in[6];
  const float* W2       = (const float*)d_in[7];
  const float* b2       = (const float*)d_in[8];

  const int n_edges = in_sizes[0] / EDGE_DIM;  // 1600000
  const int n_nodes = in_sizes[2] / NODE_DIM;  // 50000
  const int NBH = (n_edges + EPB - 1) / EPB;   // 391 hist/scatter blocks
  float* out = (float*)d_out;

  // workspace layout (~15 MB)
  char* ws = (char*)d_ws;
  size_t off = 0;
  int* bh = (int*)(ws + off);      off += (size_t)NBH * NBUCKET * 4;
  off = (off + 255) & ~(size_t)255;
  int* tot = (int*)(ws + off);     off += NBUCKET * 4;
  off = (off + 255) & ~(size_t)255;
  int* base = (int*)(ws + off);    off += (NBUCKET + 1) * 4;
  off = (off + 255) & ~(size_t)255;
  int* sorted1 = (int*)(ws + off); off += (size_t)n_edges * 4;
  off = (off + 255) & ~(size_t)255;
  int* nodeoff = (int*)(ws + off); off += (size_t)n_nodes * 4;
  off = (off + 255) & ~(size_t)255;
  int* ncount = (int*)(ws + off);  off += (size_t)n_nodes * 4;
  off = (off + 255) & ~(size_t)255;
  int* eidcsr = (int*)(ws + off);  off += (size_t)n_edges * 4;
  off = (off + 255) & ~(size_t)255;
  __bf16* W1T = (__bf16*)(ws + off); off += (size_t)HID_DIM * XDIM * 2;
  off = (off + 255) & ~(size_t)255;
  float* b1f = (float*)(ws + off);  off += HID_DIM * 4;
  off = (off + 255) & ~(size_t)255;
  __bf16* W2T = (__bf16*)(ws + off); off += (size_t)HID_DIM * OUT_DIM * 2;

  prep_hist_kernel<<<HID_DIM + OUT_DIM + NBH, 256, 0, stream>>>(
      W1, b1, W2, globals_, W1T, b1f, W2T, recv, bh, n_edges);
  col_scan_kernel<<<NBUCKET / 4, 256, 0, stream>>>(bh, tot, NBH);   // 512 waves
  base_scan_kernel<<<1, NBUCKET, 0, stream>>>(tot, base);
  scatter_kernel<<<NBH, 256, 0, stream>>>(recv, bh, base, sorted1, n_edges);
  regroup_kernel<<<NBUCKET, 256, 0, stream>>>(sorted1, base, nodeoff, ncount,
                                              eidcsr, n_nodes);
  fused_kernel<<<(n_nodes + MT - 1) / MT, 256, 0, stream>>>(
      edges, nodeoff, ncount, eidcsr, nodes, W1T, b1f, W2T, b2, out, n_nodes);
}

// Round 2
// 172.120 us; speedup vs baseline: 1.3095x; 1.3095x over previous
//
#include <hip/hip_runtime.h>

// NodeBlock: agg = segment_sum(edges[1.6M,64], recv -> 50000 nodes)
//            X = [agg | nodes] (globals folded into bias)  (50000 x 192) bf16
//            out = relu(X@W1[:192]+b1') @ W2 + b2          (f32, 50000 x 128)
//
// R21: fusion retained, concurrency fixed. R20 (256thr, 8 waves/CU) starved
// the gather (2.5 TB/s). Now 512 thr/block = 8 waves, still MT=64 tile and
// 2 blocks/CU (61.4 KB LDS) -> 16 waves/CU, ~32 KB gather loads in flight.
// Phase1: 2 colblocks/wave (B1 48 VGPR). Phase2: 1 colblock/wave.
// __launch_bounds__(512,4) caps VGPR at 128.
// Ledger (R19 split): build_x 83 | mlp 40 | scatter+regroup 22 | small+gaps ~23.

typedef __bf16 bf16x8 __attribute__((ext_vector_type(8)));
typedef __bf16 bf16x4 __attribute__((ext_vector_type(4)));
typedef __bf16 bf16x2 __attribute__((ext_vector_type(2)));
typedef float f32x4 __attribute__((ext_vector_type(4)));
typedef int i32x4 __attribute__((ext_vector_type(4)));

#define EDGE_DIM 64
#define NODE_DIM 128
#define XDIM 192     // agg(64) | nodes(128); globals folded into bias
#define XPAD 200     // row stride bf16 (uniform bank spread for b128 reads)
#define HID_DIM 256
#define OUT_DIM 128
#define NBUCKET 512
#define NPB 98       // nodes per bucket: 512*98 = 50176 >= 50000; local < 128 (7 bits)
#define EPB 4096     // edges per hist/scatter block (256 thr x 16)
#define MT 64        // M-tile of fused kernel
#define HPAD 280     // Hs row stride (bf16)

// ---------------- K1: weight prep (+bias fold) + per-block bucket histogram --
__global__ __launch_bounds__(256) void prep_hist_kernel(
    const float* __restrict__ W1, const float* __restrict__ b1,
    const float* __restrict__ W2, const float* __restrict__ glob,
    __bf16* __restrict__ W1T, float* __restrict__ b1f, __bf16* __restrict__ W2T,
    const int* __restrict__ recv, int* __restrict__ bh, int n_edges) {
  const int b = blockIdx.x, t = threadIdx.x;
  if (b < HID_DIM) {
    if (t < XDIM) {
      W1T[b * XDIM + t] = (__bf16)W1[t * HID_DIM + b];
    } else {
      // threads 192..255 == wave 3: fold globals into bias (f32 exact)
      float p = glob[t - XDIM] * W1[t * HID_DIM + b];
      for (int off = 32; off; off >>= 1) p += __shfl_xor(p, off, 64);
      if (t == XDIM) b1f[b] = b1[b] + p;
    }
    return;
  }
  if (b < HID_DIM + OUT_DIM) {
    int nn = b - HID_DIM;
    W2T[nn * HID_DIM + t] = (__bf16)W2[t * OUT_DIM + nn];
    return;
  }
  const int hb = b - (HID_DIM + OUT_DIM);
  __shared__ int h[NBUCKET];
  for (int k = t; k < NBUCKET; k += 256) h[k] = 0;
  __syncthreads();
  const int i0 = hb * EPB + t * 16;
  if (i0 + 16 <= n_edges) {
#pragma unroll
    for (int c = 0; c < 4; ++c) {
      i32x4 r4 = *(const i32x4*)(recv + i0 + c * 4);
      atomicAdd(&h[r4.x / NPB], 1);
      atomicAdd(&h[r4.y / NPB], 1);
      atomicAdd(&h[r4.z / NPB], 1);
      atomicAdd(&h[r4.w / NPB], 1);
    }
  } else {
    for (int j = 0; j < 16; ++j)
      if (i0 + j < n_edges) atomicAdd(&h[recv[i0 + j] / NPB], 1);
  }
  __syncthreads();
  for (int k = t; k < NBUCKET; k += 256) bh[(size_t)hb * NBUCKET + k] = h[k];
}

// ---------------- K2a: WAVE-PARALLEL column scan (one wave per bucket) ------
__global__ __launch_bounds__(256) void col_scan_kernel(
    int* __restrict__ bh, int* __restrict__ tot, int nbh) {
  const int bucket = (blockIdx.x * 256 + threadIdx.x) >> 6;
  const int lane = threadIdx.x & 63;
  int running = 0;
  for (int c = 0; c < nbh; c += 64) {
    const int k = c + lane;
    int v = (k < nbh) ? bh[(size_t)k * NBUCKET + bucket] : 0;
    int incl = v;
    for (int off = 1; off < 64; off <<= 1) {
      int y = __shfl_up(incl, off, 64);
      if (lane >= off) incl += y;
    }
    if (k < nbh) bh[(size_t)k * NBUCKET + bucket] = running + incl - v;
    running += __shfl(incl, 63, 64);
  }
  if (lane == 0) tot[bucket] = running;
}

// ---------------- K2b: base scan over 512 totals (1 block) ------------------
__global__ __launch_bounds__(512) void base_scan_kernel(const int* __restrict__ tot,
                                                        int* __restrict__ base) {
  const int b = threadIdx.x;
  int v = tot[b];
  __shared__ int sums[NBUCKET];
  sums[b] = v;
  __syncthreads();
  for (int off = 1; off < NBUCKET; off <<= 1) {
    int y = (b >= off) ? sums[b - off] : 0;
    __syncthreads();
    sums[b] += y;
    __syncthreads();
  }
  base[b] = sums[b] - v;  // exclusive
  if (b == NBUCKET - 1) base[NBUCKET] = sums[b];
}

// ---------------- K3: scatter packed (eid<<7)|local, LDS cursors ------------
__global__ __launch_bounds__(256) void scatter_kernel(
    const int* __restrict__ recv, const int* __restrict__ off,
    const int* __restrict__ base, int* __restrict__ sorted1, int n_edges) {
  const int kb = blockIdx.x, t = threadIdx.x;
  __shared__ int cur[NBUCKET];
  for (int k = t; k < NBUCKET; k += 256)
    cur[k] = base[k] + off[(size_t)kb * NBUCKET + k];
  __syncthreads();
  const int i0 = kb * EPB + t * 16;
  if (i0 + 16 <= n_edges) {
#pragma unroll
    for (int c = 0; c < 4; ++c) {
      i32x4 r4 = *(const i32x4*)(recv + i0 + c * 4);
      const int e0 = i0 + c * 4;
      int bk, p;
      bk = r4.x / NPB; p = atomicAdd(&cur[bk], 1);
      sorted1[p] = ((e0 + 0) << 7) | (r4.x - bk * NPB);
      bk = r4.y / NPB; p = atomicAdd(&cur[bk], 1);
      sorted1[p] = ((e0 + 1) << 7) | (r4.y - bk * NPB);
      bk = r4.z / NPB; p = atomicAdd(&cur[bk], 1);
      sorted1[p] = ((e0 + 2) << 7) | (r4.z - bk * NPB);
      bk = r4.w / NPB; p = atomicAdd(&cur[bk], 1);
      sorted1[p] = ((e0 + 3) << 7) | (r4.w - bk * NPB);
    }
  } else {
    for (int j = 0; j < 16; ++j) {
      const int i = i0 + j;
      if (i < n_edges) {
        int r = recv[i];
        int bk = r / NPB;
        int p = atomicAdd(&cur[bk], 1);
        sorted1[p] = (i << 7) | (r - bk * NPB);
      }
    }
  }
}

// ---------------- K4: regroup bucket pairs -> per-node eid lists ------------
__global__ __launch_bounds__(256) void regroup_kernel(
    const int* __restrict__ sorted1, const int* __restrict__ base,
    int* __restrict__ nodeoff, int* __restrict__ ncount,
    int* __restrict__ eidcsr, int n_nodes) {
  const int b = blockIdx.x, t = threadIdx.x;
  __shared__ int cnt[NPB];
  __shared__ int loff[NPB];
  if (t < NPB) cnt[t] = 0;
  __syncthreads();
  const int s = base[b], e = base[b + 1];
  const int nb_ = b * NPB;
  for (int j = s + t; j < e; j += 256) atomicAdd(&cnt[sorted1[j] & 127], 1);
  __syncthreads();
  if (t == 0) {
    int run = 0;
#pragma unroll
    for (int k = 0; k < NPB; ++k) { loff[k] = run; run += cnt[k]; }
  }
  __syncthreads();
  if (t < NPB) {
    const int node = nb_ + t;
    if (node < n_nodes) { nodeoff[node] = s + loff[t]; ncount[node] = cnt[t]; }
    cnt[t] = 0;  // reuse as cursor
  }
  __syncthreads();
  for (int j = s + t; j < e; j += 256) {
    const int p = sorted1[j];
    const int local = p & 127;
    const int slot = atomicAdd(&cnt[local], 1);
    eidcsr[s + loff[local] + slot] = p >> 7;
  }
}

// ---------------- K5: FUSED gather -> LDS X tile -> MLP (8 waves) -----------
#define NTLOAD(i) __builtin_nontemporal_load((const f32x4*)(edges + (size_t)(i) * EDGE_DIM + l15 * 4))

__global__ __launch_bounds__(512, 4) void fused_kernel(
    const float* __restrict__ edges, const int* __restrict__ nodeoff,
    const int* __restrict__ ncount, const int* __restrict__ eid,
    const float* __restrict__ nodes,
    const __bf16* __restrict__ W1T, const float* __restrict__ b1f,
    const __bf16* __restrict__ W2T, const float* __restrict__ b2,
    float* __restrict__ out, int M) {
  __shared__ __bf16 Xs[MT][XPAD];   // 25.6 KB
  __shared__ __bf16 Hs[MT][HPAD];   // 35.8 KB
  const int wave = threadIdx.x >> 6;   // 0..7
  const int lane = threadIdx.x & 63;
  const int q = lane >> 4;    // quarter-wave id (memory pipeline lane)
  const int l15 = lane & 15;
  const int lk = q;           // k-chunk id in MFMA fragments
  const int Mbase0 = blockIdx.x * MT;

  // ---- gather phase: wave w builds rows [w*8, w*8+8) of Xs ----------------
  for (int r = wave * 8; r < wave * 8 + 8; ++r) {
    const int node = Mbase0 + r;
    int s = 0, e = 0;
    if (node < M) { s = nodeoff[node]; e = s + ncount[node]; }
    f32x4 z = {0.f, 0.f, 0.f, 0.f};
    f32x4 a0 = z, a1 = z, a2 = z, a3 = z, a4 = z, a5 = z, a6 = z, a7 = z;
    int j = s + q;
    int i0 = (j      < e) ? eid[j]      : 0;
    int i1 = (j + 4  < e) ? eid[j + 4]  : 0;
    int i2 = (j + 8  < e) ? eid[j + 8]  : 0;
    int i3 = (j + 12 < e) ? eid[j + 12] : 0;
    int i4 = (j + 16 < e) ? eid[j + 16] : 0;
    int i5 = (j + 20 < e) ? eid[j + 20] : 0;
    int i6 = (j + 24 < e) ? eid[j + 24] : 0;
    int i7 = (j + 28 < e) ? eid[j + 28] : 0;
    while (j + 28 < e) {  // 8 x 256B loads in flight per wave
      f32x4 v0 = NTLOAD(i0);
      f32x4 v1 = NTLOAD(i1);
      f32x4 v2 = NTLOAD(i2);
      f32x4 v3 = NTLOAD(i3);
      f32x4 v4 = NTLOAD(i4);
      f32x4 v5 = NTLOAD(i5);
      f32x4 v6 = NTLOAD(i6);
      f32x4 v7 = NTLOAD(i7);
      int n0 = (j + 32 < e) ? eid[j + 32] : 0;
      int n1 = (j + 36 < e) ? eid[j + 36] : 0;
      int n2 = (j + 40 < e) ? eid[j + 40] : 0;
      int n3 = (j + 44 < e) ? eid[j + 44] : 0;
      int n4 = (j + 48 < e) ? eid[j + 48] : 0;
      int n5 = (j + 52 < e) ? eid[j + 52] : 0;
      int n6 = (j + 56 < e) ? eid[j + 56] : 0;
      int n7 = (j + 60 < e) ? eid[j + 60] : 0;
      a0 += v0; a1 += v1; a2 += v2; a3 += v3;
      a4 += v4; a5 += v5; a6 += v6; a7 += v7;
      i0 = n0; i1 = n1; i2 = n2; i3 = n3;
      i4 = n4; i5 = n5; i6 = n6; i7 = n7;
      j += 32;
    }
    if (j      < e) a0 += NTLOAD(i0);
    if (j + 4  < e) a1 += NTLOAD(i1);
    if (j + 8  < e) a2 += NTLOAD(i2);
    if (j + 12 < e) a3 += NTLOAD(i3);
    if (j + 16 < e) a4 += NTLOAD(i4);
    if (j + 20 < e) a5 += NTLOAD(i5);
    if (j + 24 < e) a6 += NTLOAD(i6);

    a0 += a1; a2 += a3; a4 += a5; a6 += a7;
    a0 += a2; a4 += a6; a0 += a4;
#pragma unroll
    for (int c = 0; c < 4; ++c) {  // reduce across the 4 quarters
      float v = a0[c];
      v += __shfl_xor(v, 16, 64);
      v += __shfl_xor(v, 32, 64);
      a0[c] = v;
    }
    if (q == 0) {
      bf16x4 o;
      o[0] = (__bf16)a0[0]; o[1] = (__bf16)a0[1];
      o[2] = (__bf16)a0[2]; o[3] = (__bf16)a0[3];
      *(bf16x4*)(&Xs[r][l15 * 4]) = o;  // agg cols 0..63
    }
    bf16x2 nb;
    if (node < M) {
      float2 nv = *(const float2*)(nodes + (size_t)node * NODE_DIM + lane * 2);
      nb[0] = (__bf16)nv.x; nb[1] = (__bf16)nv.y;
    } else {
      nb[0] = (__bf16)0.f; nb[1] = (__bf16)0.f;
    }
    *(bf16x2*)(&Xs[r][EDGE_DIM + lane * 2]) = nb;  // node cols 64..191
  }
  __syncthreads();

  {  // phase 1: H = relu(Xs @ W1[:192] + b1') -> LDS (K = 192, 6 ks steps)
    bf16x8 B1[2][6];
    float bias1[2];
    const int colbase = wave * 32;
#pragma unroll
    for (int cb = 0; cb < 2; ++cb) {
      const int col = colbase + cb * 16 + l15;
      const __bf16* wrow = W1T + col * XDIM + lk * 8;
#pragma unroll
      for (int ks = 0; ks < 6; ++ks) B1[cb][ks] = *(const bf16x8*)(wrow + ks * 32);
      bias1[cb] = b1f[col];
    }
#pragma unroll
    for (int mb = 0; mb < 4; ++mb) {
      f32x4 acc[2];
#pragma unroll
      for (int cb = 0; cb < 2; ++cb) {
        f32x4 ini = {bias1[cb], bias1[cb], bias1[cb], bias1[cb]};
        acc[cb] = ini;
      }
      const __bf16* xrow = &Xs[mb * 16 + l15][lk * 8];
#pragma unroll
      for (int ks = 0; ks < 6; ++ks) {
        bf16x8 A = *(const bf16x8*)(xrow + ks * 32);
#pragma unroll
        for (int cb = 0; cb < 2; ++cb)
          acc[cb] = __builtin_amdgcn_mfma_f32_16x16x32_bf16(A, B1[cb][ks], acc[cb], 0, 0, 0);
      }
#pragma unroll
      for (int cb = 0; cb < 2; ++cb) {
#pragma unroll
        for (int r = 0; r < 4; ++r) {
          float v = acc[cb][r];
          Hs[mb * 16 + lk * 4 + r][colbase + cb * 16 + l15] = (__bf16)(v > 0.f ? v : 0.f);
        }
      }
    }
  }
  __syncthreads();
  {  // phase 2: out = H @ W2 + b2 (1 colblock of 16 per wave: 8*16 = 128)
    bf16x8 B2[8];
    const int col = wave * 16 + l15;
    const __bf16* wrow = W2T + col * HID_DIM + lk * 8;
#pragma unroll
    for (int ks = 0; ks < 8; ++ks) B2[ks] = *(const bf16x8*)(wrow + ks * 32);
    const float bias2 = b2[col];
#pragma unroll
    for (int mb = 0; mb < 4; ++mb) {
      const int Mbase = Mbase0 + mb * 16;
      f32x4 acc = {bias2, bias2, bias2, bias2};
#pragma unroll
      for (int ks = 0; ks < 8; ++ks) {
        bf16x8 A = *(const bf16x8*)(&Hs[mb * 16 + l15][lk * 8 + ks * 32]);
        acc = __builtin_amdgcn_mfma_f32_16x16x32_bf16(A, B2[ks], acc, 0, 0, 0);
      }
#pragma unroll
      for (int r = 0; r < 4; ++r) {
        const int row = Mbase + lk * 4 + r;
        if (row < M) out[(size_t)row * OUT_DIM + col] = acc[r];
      }
    }
  }
}

extern "C" void kernel_launch(void* const* d_in, const int* in_sizes, int n_in,
                              void* d_out, int out_size, void* d_ws, size_t ws_size,
                              hipStream_t stream) {
  const float* edges    = (const float*)d_in[0];
  const int*   recv     = (const int*)d_in[1];
  const float* nodes    = (const float*)d_in[2];
  const float* globals_ = (const float*)d_in[3];
  const float* W1       = (const float*)d_in[5];
  const float* b1       = (const float*)d_in[6];
  const float* W2       = (const float*)d_in[7];
  const float* b2       = (const float*)d_in[8];

  const int n_edges = in_sizes[0] / EDGE_DIM;  // 1600000
  const int n_nodes = in_sizes[2] / NODE_DIM;  // 50000
  const int NBH = (n_edges + EPB - 1) / EPB;   // 391 hist/scatter blocks
  float* out = (float*)d_out;

  // workspace layout (~15 MB)
  char* ws = (char*)d_ws;
  size_t off = 0;
  int* bh = (int*)(ws + off);      off += (size_t)NBH * NBUCKET * 4;
  off = (off + 255) & ~(size_t)255;
  int* tot = (int*)(ws + off);     off += NBUCKET * 4;
  off = (off + 255) & ~(size_t)255;
  int* base = (int*)(ws + off);    off += (NBUCKET + 1) * 4;
  off = (off + 255) & ~(size_t)255;
  int* sorted1 = (int*)(ws + off); off += (size_t)n_edges * 4;
  off = (off + 255) & ~(size_t)255;
  int* nodeoff = (int*)(ws + off); off += (size_t)n_nodes * 4;
  off = (off + 255) & ~(size_t)255;
  int* ncount = (int*)(ws + off);  off += (size_t)n_nodes * 4;
  off = (off + 255) & ~(size_t)255;
  int* eidcsr = (int*)(ws + off);  off += (size_t)n_edges * 4;
  off = (off + 255) & ~(size_t)255;
  __bf16* W1T = (__bf16*)(ws + off); off += (size_t)HID_DIM * XDIM * 2;
  off = (off + 255) & ~(size_t)255;
  float* b1f = (float*)(ws + off);  off += HID_DIM * 4;
  off = (off + 255) & ~(size_t)255;
  __bf16* W2T = (__bf16*)(ws + off); off += (size_t)HID_DIM * OUT_DIM * 2;

  prep_hist_kernel<<<HID_DIM + OUT_DIM + NBH, 256, 0, stream>>>(
      W1, b1, W2, globals_, W1T, b1f, W2T, recv, bh, n_edges);
  col_scan_kernel<<<NBUCKET / 4, 256, 0, stream>>>(bh, tot, NBH);   // 512 waves
  base_scan_kernel<<<1, NBUCKET, 0, stream>>>(tot, base);
  scatter_kernel<<<NBH, 256, 0, stream>>>(recv, bh, base, sorted1, n_edges);
  regroup_kernel<<<NBUCKET, 256, 0, stream>>>(sorted1, base, nodeoff, ncount,
                                              eidcsr, n_nodes);
  fused_kernel<<<(n_nodes + MT - 1) / MT, 512, 0, stream>>>(
      edges, nodeoff, ncount, eidcsr, nodes, W1T, b1f, W2T, b2, out, n_nodes);
}